// Round 8
// baseline (226.268 us; speedup 1.0000x reference)
//
#include <hip/hip_runtime.h>
#include <math.h>

#define NB 2
#define NL 256
#define DM 512
#define NH 8
#define DQ 64

// ---------------------------------------------------------------------------
// K1: QKV projection GEMM. 64x64 tile, K-tile 32, thread tile 4x4, b128 LDS
// reads on both operands (2 LDS : 16 FMA per kk). grid (8,8,3) = 192 blocks.
// ---------------------------------------------------------------------------
__global__ __launch_bounds__(256) void qkv_gemm(
    const float* __restrict__ xq, const float* __restrict__ xk,
    const float* __restrict__ xv,
    const float* __restrict__ Wq, const float* __restrict__ Wk,
    const float* __restrict__ Wv,
    const float* __restrict__ bq, const float* __restrict__ bk,
    const float* __restrict__ bv,
    float* __restrict__ q, float* __restrict__ k, float* __restrict__ v)
{
    int z = blockIdx.z;
    const float* X = (z == 0) ? xq : (z == 1) ? xk : xv;
    const float* W = (z == 0) ? Wq : (z == 1) ? Wk : Wv;
    const float* bias = (z == 0) ? bq : (z == 1) ? bk : bv;
    float* O = (z == 0) ? q : (z == 1) ? k : v;

    __shared__ float As[32][68];   // [k][m], row stride 68 (16B-aligned, bank-skewed)
    __shared__ float Bs[32][68];   // [k][n]

    int tid = threadIdx.x;
    int tx = tid & 15, ty = tid >> 4;
    int m0 = blockIdx.y * 64, n0 = blockIdx.x * 64;

    float acc[4][4] = {};

    for (int k0 = 0; k0 < 512; k0 += 32) {
        {   // A: lane=m mapping; wave w handles k-quad w. Conflict-free scalar writes.
            int m = tid & 63;
            int kq = tid >> 6;          // 0..3
            const float* src = X + (m0 + m) * 512 + k0 + kq * 4;
            float4 a0 = *(const float4*)(src);
            float4 a1 = *(const float4*)(src + 16);
            As[kq * 4 + 0][m] = a0.x; As[kq * 4 + 1][m] = a0.y;
            As[kq * 4 + 2][m] = a0.z; As[kq * 4 + 3][m] = a0.w;
            As[kq * 4 + 16][m] = a1.x; As[kq * 4 + 17][m] = a1.y;
            As[kq * 4 + 18][m] = a1.z; As[kq * 4 + 19][m] = a1.w;
        }
        {   // B: row-major copy, b128 writes
            int r = tid >> 4, c4 = (tid & 15) * 4;
            float4 b0 = *(const float4*)(W + (k0 + r) * 512 + n0 + c4);
            float4 b1 = *(const float4*)(W + (k0 + r + 16) * 512 + n0 + c4);
            *(float4*)&Bs[r][c4] = b0;
            *(float4*)&Bs[r + 16][c4] = b1;
        }
        __syncthreads();
        #pragma unroll
        for (int kk = 0; kk < 32; kk++) {
            float4 a = *(const float4*)&As[kk][ty * 4];
            float4 bb = *(const float4*)&Bs[kk][tx * 4];
            acc[0][0] += a.x * bb.x; acc[0][1] += a.x * bb.y;
            acc[0][2] += a.x * bb.z; acc[0][3] += a.x * bb.w;
            acc[1][0] += a.y * bb.x; acc[1][1] += a.y * bb.y;
            acc[1][2] += a.y * bb.z; acc[1][3] += a.y * bb.w;
            acc[2][0] += a.z * bb.x; acc[2][1] += a.z * bb.y;
            acc[2][2] += a.z * bb.z; acc[2][3] += a.z * bb.w;
            acc[3][0] += a.w * bb.x; acc[3][1] += a.w * bb.y;
            acc[3][2] += a.w * bb.z; acc[3][3] += a.w * bb.w;
        }
        __syncthreads();
    }

    #pragma unroll
    for (int i = 0; i < 4; i++) {
        int m = m0 + ty * 4 + i;
        int b = m >> 8, l = m & 255;
        #pragma unroll
        for (int j = 0; j < 4; j++) {
            int n = n0 + tx * 4 + j;
            int h = n >> 6, d = n & 63;
            O[((b * NH + h) * NL + l) * DQ + d] = acc[i][j] + bias[n];
        }
    }
}

// ---------------------------------------------------------------------------
// K2: fused attn softmax + u precompute. blockIdx.x<256 -> attn row, else u.
// ---------------------------------------------------------------------------
__global__ __launch_bounds__(256) void attn_u_kernel(
    const float* __restrict__ q, const float* __restrict__ k,
    const float* __restrict__ mask, float* __restrict__ attn_o,
    const float* __restrict__ v, const float* __restrict__ Wre,
    const float* __restrict__ Wim, float2* __restrict__ u)
{
    int h = blockIdx.y, b = blockIdx.z;
    int tid = threadIdx.x;
    __shared__ float smem[264];

    if (blockIdx.x < 256) {
        int qi = blockIdx.x;
        int wv = tid >> 6, lane = tid & 63;
        float* qrow = smem;
        float* wred = smem + 256;
        float* wsum = smem + 260;

        if (tid < 16)
            ((float4*)qrow)[tid] = ((const float4*)(q + ((b * NH + h) * NL + qi) * DQ))[tid];
        __syncthreads();

        const float4* kp = (const float4*)(k + ((b * NH + h) * NL + tid) * DQ);
        float acc = 0.f;
        #pragma unroll
        for (int d4 = 0; d4 < 16; d4++) {
            float4 kv = kp[d4];
            float4 qv = ((const float4*)qrow)[d4];
            acc += qv.x * kv.x + qv.y * kv.y + qv.z * kv.z + qv.w * kv.w;
        }
        acc *= 0.125f;

        float mv = mask[(b * NL + qi) * NL + tid];
        acc -= (mv == 1.0f) ? INFINITY : mv;

        float mx = acc;
        #pragma unroll
        for (int o = 32; o; o >>= 1) mx = fmaxf(mx, __shfl_xor(mx, o, 64));
        if (lane == 0) wred[wv] = mx;
        __syncthreads();
        mx = fmaxf(fmaxf(wred[0], wred[1]), fmaxf(wred[2], wred[3]));

        float e = __expf(acc - mx);
        float s = e;
        #pragma unroll
        for (int o = 32; o; o >>= 1) s += __shfl_xor(s, o, 64);
        if (lane == 0) wsum[wv] = s;
        __syncthreads();
        s = wsum[0] + wsum[1] + wsum[2] + wsum[3];

        attn_o[((b * NH + h) * NL + qi) * NL + tid] = e * __builtin_amdgcn_rcpf(s);
    } else {
        int xi = blockIdx.x - 256;          // 0..63
        int e = tid & 63, tq = tid >> 6;
        int t = xi * 4 + tq;
        float (*vrow)[64] = (float (*)[64])smem;

        const float* vp = v + ((b * NH + h) * NL + t) * DQ;
        vrow[tq][e] = vp[e];
        __syncthreads();

        const float* wr = Wre + h * 4096 + e;
        const float* wi = Wim + h * 4096 + e;
        float ar = 0.f, ai = 0.f;
        #pragma unroll
        for (int d = 0; d < 64; d++) {
            float vv = vrow[tq][d];
            ar += vv * wr[d * 64];
            ai += vv * wi[d * 64];
        }
        u[((b * NH + h) * NL + t) * DQ + e] = make_float2(ar, ai);
    }
}

// ---------------------------------------------------------------------------
// K3: EUNN recurrence, 2 state elements per lane, recurrences interleaved by
// lane parity; cross-lane exchange = whole-wave rotate-by-2 via chained DPP
// wave_rol:1 / wave_ror:1 (pure VALU). attn row staged in LDS as float4 rows
// with stride 65 float4 (bank-skewed, b128 read amortized over 4 steps).
// modrelu: EXACT reference form relu(m+b)*rcp(m+1e-5) — do NOT fold the
// denominator into rsqrt; the 1e-5 offset compounds over 256 steps (R7 bug).
// ---------------------------------------------------------------------------
__device__ __forceinline__ float rot_up2(float x) {   // lane i <- lane (i+2)%64
    int v = __builtin_amdgcn_mov_dpp(__float_as_int(x), 0x134, 0xF, 0xF, true);
    v = __builtin_amdgcn_mov_dpp(v, 0x134, 0xF, 0xF, true);
    return __int_as_float(v);
}
__device__ __forceinline__ float rot_dn2(float x) {   // lane i <- lane (i-2)%64
    int v = __builtin_amdgcn_mov_dpp(__float_as_int(x), 0x13C, 0xF, 0xF, true);
    v = __builtin_amdgcn_mov_dpp(v, 0x13C, 0xF, 0xF, true);
    return __int_as_float(v);
}

__global__ __launch_bounds__(256) void rnn_kernel(
    const float* __restrict__ attn_f, const float2* __restrict__ u,
    const float* __restrict__ theta, const float* __restrict__ phi,
    const float* __restrict__ rnn_bias, float* __restrict__ rnn_out)
{
    int tid = threadIdx.x;
    int wv = tid >> 6;
    int lane = tid & 63;
    int par = lane & 1;
    int p = lane >> 1;                          // 0..31
    int rec = blockIdx.x * 8 + wv * 2 + par;    // 0..4095
    int qi = rec & 255, h = (rec >> 8) & 7, b = rec >> 11;

    const float* tb = theta + h * 64;   // [c][j] = [2][32]
    const float* pb = phi + h * 64;

    // stage-0 pair j = p
    float th0 = tb[p], ph0 = pb[p];
    float c0 = cosf(th0), s0 = sinf(th0);
    float cp0 = cosf(ph0), sp0 = sinf(ph0);
    float W0ar = -s0 * cp0, W0ai = -s0 * sp0;   // coeff on e1 in na
    float W0br =  s0 * cp0, W0bi = -s0 * sp0;   // coeff on e0 in nb

    // stage-1 pair j = p  (output element 2p+1)
    float th1 = tb[32 + p], ph1 = pb[32 + p];
    float c1 = cosf(th1), s1 = sinf(th1);
    float W1ar = -s1 * cosf(ph1), W1ai = -s1 * sinf(ph1);   // on f1

    // stage-1 pair pm = p-1 (output element 2p)
    int pm = (p + 31) & 31;
    float th1m = tb[32 + pm], ph1m = pb[32 + pm];
    float c1m = cosf(th1m), s1m = sinf(th1m);
    float W1br = s1m * cosf(ph1m), W1bi = -s1m * sinf(ph1m); // on f2

    float bias0 = rnn_bias[h * 64 + 2 * p];
    float bias1 = rnn_bias[h * 64 + 2 * p + 1];

    // attn rows: 8 recs x 256 steps, padded row stride 65 float4 (260 floats)
    __shared__ float4 arow4[8][65];
    {
        const float4* ap = (const float4*)(attn_f + (size_t)blockIdx.x * 8 * 256);
        int i0 = tid * 2, i1 = tid * 2 + 1;
        arow4[i0 >> 6][i0 & 63] = ap[i0];
        arow4[i1 >> 6][i1 & 63] = ap[i1];
    }
    __syncthreads();
    const float4* arc4 = arow4[wv * 2 + par];

    // u row: 64 float2 = 32 float4 per step; lane pair (2p,2p+1) reads float4 p
    const float4* up4 = (const float4*)(u + (size_t)((b * NH + h) * NL) * DQ) + p;

    float e0r = 0.f, e0i = 0.f, e1r = 0.f, e1i = 0.f;
    #pragma unroll 2
    for (int g = 0; g < 64; g++) {
        float4 a4 = arc4[g];
        #pragma unroll
        for (int tt = 0; tt < 4; tt++) {
            float4 uu = up4[(g * 4 + tt) * 32];
            float a_t = (tt == 0) ? a4.x : (tt == 1) ? a4.y : (tt == 2) ? a4.z : a4.w;

            // stage 0 (in-lane)
            float na_r = c0 * e0r + (W0ar * e1r - W0ai * e1i);
            float na_i = c0 * e0i + (W0ar * e1i + W0ai * e1r);
            float nb_r = c0 * e1r + (W0br * e0r - W0bi * e0i);
            float nb_i = c0 * e1i + (W0br * e0i + W0bi * e0r);

            // neighbor exchange via DPP (pure VALU)
            float f1r = rot_up2(na_r), f1i = rot_up2(na_i);   // h1[2p+2]
            float f2r = rot_dn2(nb_r), f2i = rot_dn2(nb_i);   // h1[2p-1]

            // stage 1
            float z1r = c1 * nb_r + (W1ar * f1r - W1ai * f1i);
            float z1i = c1 * nb_i + (W1ar * f1i + W1ai * f1r);
            float z0r = c1m * na_r + (W1br * f2r - W1bi * f2i);
            float z0i = c1m * na_i + (W1br * f2i + W1bi * f2r);

            // + a_t * u_t
            z0r += a_t * uu.x; z0i += a_t * uu.y;
            z1r += a_t * uu.z; z1i += a_t * uu.w;

            // modrelu — exact reference form
            float mm0 = z0r * z0r + z0i * z0i;
            float m0 = __builtin_amdgcn_sqrtf(mm0);
            float sc0 = fmaxf(m0 + bias0, 0.f) * __builtin_amdgcn_rcpf(m0 + 1e-5f);
            e0r = z0r * sc0; e0i = z0i * sc0;

            float mm1 = z1r * z1r + z1i * z1i;
            float m1 = __builtin_amdgcn_sqrtf(mm1);
            float sc1 = fmaxf(m1 + bias1, 0.f) * __builtin_amdgcn_rcpf(m1 + 1e-5f);
            e1r = z1r * sc1; e1i = z1i * sc1;
        }
    }

    // real parts -> (B, L, DM) row-major
    float2 o = make_float2(e0r, e1r);
    *(float2*)&rnn_out[(size_t)(b * NL + qi) * DM + h * DQ + 2 * p] = o;
}

// ---------------------------------------------------------------------------
// K4: output projection. 32x64 tile, K-tile 32, thread tile 2x4.
// grid (8,16) = 128 blocks.
// ---------------------------------------------------------------------------
__global__ __launch_bounds__(256) void out_gemm(
    const float* __restrict__ A, const float* __restrict__ W,
    const float* __restrict__ bias, float* __restrict__ C)
{
    __shared__ float As[32][33];
    __shared__ float Bs[32][68];

    int tid = threadIdx.x;
    int tx = tid & 15, ty = tid >> 4;
    int m0 = blockIdx.y * 32, n0 = blockIdx.x * 64;

    float acc[2][4] = {};

    for (int k0 = 0; k0 < 512; k0 += 32) {
        {
            int r = tid >> 3, c4 = (tid & 7) * 4;
            const float4 av = *(const float4*)(A + (m0 + r) * 512 + k0 + c4);
            As[c4 + 0][r] = av.x; As[c4 + 1][r] = av.y;
            As[c4 + 2][r] = av.z; As[c4 + 3][r] = av.w;
        }
        {
            int r = tid >> 4, c4 = (tid & 15) * 4;
            float4 b0 = *(const float4*)(W + (k0 + r) * 512 + n0 + c4);
            float4 b1 = *(const float4*)(W + (k0 + r + 16) * 512 + n0 + c4);
            *(float4*)&Bs[r][c4] = b0;
            *(float4*)&Bs[r + 16][c4] = b1;
        }
        __syncthreads();
        #pragma unroll
        for (int kk = 0; kk < 32; kk++) {
            float a0 = As[kk][ty * 2 + 0];
            float a1 = As[kk][ty * 2 + 1];
            float4 bb = *(const float4*)&Bs[kk][tx * 4];
            acc[0][0] += a0 * bb.x; acc[0][1] += a0 * bb.y;
            acc[0][2] += a0 * bb.z; acc[0][3] += a0 * bb.w;
            acc[1][0] += a1 * bb.x; acc[1][1] += a1 * bb.y;
            acc[1][2] += a1 * bb.z; acc[1][3] += a1 * bb.w;
        }
        __syncthreads();
    }

    #pragma unroll
    for (int i = 0; i < 2; i++) {
        int m = m0 + ty * 2 + i;
        #pragma unroll
        for (int j = 0; j < 4; j++) {
            int n = n0 + tx * 4 + j;
            C[m * 512 + n] = acc[i][j] + bias[n];
        }
    }
}

// ---------------------------------------------------------------------------
extern "C" void kernel_launch(void* const* d_in, const int* in_sizes, int n_in,
                              void* d_out, int out_size, void* d_ws, size_t ws_size,
                              hipStream_t stream)
{
    const float* x_q  = (const float*)d_in[0];
    const float* x_k  = (const float*)d_in[1];
    const float* x_v  = (const float*)d_in[2];
    const float* mask = (const float*)d_in[3];
    const float* Wq   = (const float*)d_in[4];
    const float* bq   = (const float*)d_in[5];
    const float* Wk   = (const float*)d_in[6];
    const float* bk   = (const float*)d_in[7];
    const float* Wv   = (const float*)d_in[8];
    const float* bv   = (const float*)d_in[9];
    const float* Wo   = (const float*)d_in[10];
    const float* bo   = (const float*)d_in[11];
    const float* theta= (const float*)d_in[12];
    const float* phi  = (const float*)d_in[13];
    const float* Wre  = (const float*)d_in[14];
    const float* Wim  = (const float*)d_in[15];
    const float* rb   = (const float*)d_in[16];

    float* ws = (float*)d_ws;
    float*  q_ws    = ws;                       // 262144 f
    float*  k_ws    = ws + 262144;              // 262144 f
    float*  v_ws    = ws + 524288;              // 262144 f
    float2* u_ws    = (float2*)(ws + 786432);   // 262144 float2
    float*  rnn_o   = ws + 1310720;             // 262144 f

    float* out_o  = (float*)d_out;              // (2,256,512)
    float* attn_o = out_o + NB * NL * DM;       // (2,8,256,256)

    qkv_gemm<<<dim3(8, 8, 3), 256, 0, stream>>>(
        x_q, x_k, x_v, Wq, Wk, Wv, bq, bk, bv, q_ws, k_ws, v_ws);

    attn_u_kernel<<<dim3(320, NH, NB), 256, 0, stream>>>(
        q_ws, k_ws, mask, attn_o, v_ws, Wre, Wim, u_ws);

    rnn_kernel<<<dim3(512), 256, 0, stream>>>(
        attn_o, u_ws, theta, phi, rb, rnn_o);

    out_gemm<<<dim3(8, 16), 256, 0, stream>>>(rnn_o, Wo, bo, out_o);
}

// Round 9
// 216.676 us; speedup vs baseline: 1.0443x; 1.0443x over previous
//
#include <hip/hip_runtime.h>
#include <math.h>

#define NB 2
#define NL 256
#define DM 512
#define NH 8
#define DQ 64

// ---------------------------------------------------------------------------
// K1: QKV projection GEMM. 64x64 tile, K-tile 32, thread tile 4x4, b128 LDS
// reads. grid (8,8,3). k (z==1) is written TRANSPOSED as (b,h,d,t) so attn's
// per-key dot reads are lane-coalesced.
// ---------------------------------------------------------------------------
__global__ __launch_bounds__(256) void qkv_gemm(
    const float* __restrict__ xq, const float* __restrict__ xk,
    const float* __restrict__ xv,
    const float* __restrict__ Wq, const float* __restrict__ Wk,
    const float* __restrict__ Wv,
    const float* __restrict__ bq, const float* __restrict__ bk,
    const float* __restrict__ bv,
    float* __restrict__ q, float* __restrict__ k, float* __restrict__ v)
{
    int z = blockIdx.z;
    const float* X = (z == 0) ? xq : (z == 1) ? xk : xv;
    const float* W = (z == 0) ? Wq : (z == 1) ? Wk : Wv;
    const float* bias = (z == 0) ? bq : (z == 1) ? bk : bv;
    float* O = (z == 0) ? q : (z == 1) ? k : v;

    __shared__ float As[32][68];
    __shared__ float Bs[32][68];

    int tid = threadIdx.x;
    int tx = tid & 15, ty = tid >> 4;
    int m0 = blockIdx.y * 64, n0 = blockIdx.x * 64;

    float acc[4][4] = {};

    for (int k0 = 0; k0 < 512; k0 += 32) {
        {
            int m = tid & 63;
            int kq = tid >> 6;
            const float* src = X + (m0 + m) * 512 + k0 + kq * 4;
            float4 a0 = *(const float4*)(src);
            float4 a1 = *(const float4*)(src + 16);
            As[kq * 4 + 0][m] = a0.x; As[kq * 4 + 1][m] = a0.y;
            As[kq * 4 + 2][m] = a0.z; As[kq * 4 + 3][m] = a0.w;
            As[kq * 4 + 16][m] = a1.x; As[kq * 4 + 17][m] = a1.y;
            As[kq * 4 + 18][m] = a1.z; As[kq * 4 + 19][m] = a1.w;
        }
        {
            int r = tid >> 4, c4 = (tid & 15) * 4;
            float4 b0 = *(const float4*)(W + (k0 + r) * 512 + n0 + c4);
            float4 b1 = *(const float4*)(W + (k0 + r + 16) * 512 + n0 + c4);
            *(float4*)&Bs[r][c4] = b0;
            *(float4*)&Bs[r + 16][c4] = b1;
        }
        __syncthreads();
        #pragma unroll
        for (int kk = 0; kk < 32; kk++) {
            float4 a = *(const float4*)&As[kk][ty * 4];
            float4 bb = *(const float4*)&Bs[kk][tx * 4];
            acc[0][0] += a.x * bb.x; acc[0][1] += a.x * bb.y;
            acc[0][2] += a.x * bb.z; acc[0][3] += a.x * bb.w;
            acc[1][0] += a.y * bb.x; acc[1][1] += a.y * bb.y;
            acc[1][2] += a.y * bb.z; acc[1][3] += a.y * bb.w;
            acc[2][0] += a.z * bb.x; acc[2][1] += a.z * bb.y;
            acc[2][2] += a.z * bb.z; acc[2][3] += a.z * bb.w;
            acc[3][0] += a.w * bb.x; acc[3][1] += a.w * bb.y;
            acc[3][2] += a.w * bb.z; acc[3][3] += a.w * bb.w;
        }
        __syncthreads();
    }

    #pragma unroll
    for (int i = 0; i < 4; i++) {
        int m = m0 + ty * 4 + i;
        int b = m >> 8, l = m & 255;
        #pragma unroll
        for (int j = 0; j < 4; j++) {
            int n = n0 + tx * 4 + j;
            int h = n >> 6, d = n & 63;
            float val = acc[i][j] + bias[n];
            if (z == 1)
                O[((b * NH + h) * DQ + d) * NL + l] = val;   // kT: (b,h,d,t)
            else
                O[((b * NH + h) * NL + l) * DQ + d] = val;
        }
    }
}

// ---------------------------------------------------------------------------
// K2: fused attn softmax + u precompute. blockIdx.x<256 -> attn row, else u.
// attn reads k from the TRANSPOSED layout: lane t reads kT[d*256+t], fully
// coalesced (4 lines/instruction instead of 64).
// ---------------------------------------------------------------------------
__global__ __launch_bounds__(256) void attn_u_kernel(
    const float* __restrict__ q, const float* __restrict__ kT,
    const float* __restrict__ mask, float* __restrict__ attn_o,
    const float* __restrict__ v, const float* __restrict__ Wre,
    const float* __restrict__ Wim, float2* __restrict__ u)
{
    int h = blockIdx.y, b = blockIdx.z;
    int tid = threadIdx.x;
    __shared__ float smem[264];

    if (blockIdx.x < 256) {
        int qi = blockIdx.x;
        int wv = tid >> 6, lane = tid & 63;
        float* qrow = smem;
        float* wred = smem + 256;
        float* wsum = smem + 260;

        if (tid < 16)
            ((float4*)qrow)[tid] = ((const float4*)(q + ((b * NH + h) * NL + qi) * DQ))[tid];
        __syncthreads();

        const float* kp = kT + (size_t)((b * NH + h) * DQ) * NL + tid;
        float acc = 0.f;
        #pragma unroll
        for (int d = 0; d < 64; d++) acc += qrow[d] * kp[d * NL];
        acc *= 0.125f;

        float mv = mask[(b * NL + qi) * NL + tid];
        acc -= (mv == 1.0f) ? INFINITY : mv;

        float mx = acc;
        #pragma unroll
        for (int o = 32; o; o >>= 1) mx = fmaxf(mx, __shfl_xor(mx, o, 64));
        if (lane == 0) wred[wv] = mx;
        __syncthreads();
        mx = fmaxf(fmaxf(wred[0], wred[1]), fmaxf(wred[2], wred[3]));

        float e = __expf(acc - mx);
        float s = e;
        #pragma unroll
        for (int o = 32; o; o >>= 1) s += __shfl_xor(s, o, 64);
        if (lane == 0) wsum[wv] = s;
        __syncthreads();
        s = wsum[0] + wsum[1] + wsum[2] + wsum[3];

        attn_o[((b * NH + h) * NL + qi) * NL + tid] = e * __builtin_amdgcn_rcpf(s);
    } else {
        int xi = blockIdx.x - 256;          // 0..63
        int e = tid & 63, tq = tid >> 6;
        int t = xi * 4 + tq;
        float (*vrow)[64] = (float (*)[64])smem;

        const float* vp = v + ((b * NH + h) * NL + t) * DQ;
        vrow[tq][e] = vp[e];
        __syncthreads();

        const float* wr = Wre + h * 4096 + e;
        const float* wi = Wim + h * 4096 + e;
        float ar = 0.f, ai = 0.f;
        #pragma unroll
        for (int d = 0; d < 64; d++) {
            float vv = vrow[tq][d];
            ar += vv * wr[d * 64];
            ai += vv * wi[d * 64];
        }
        u[((b * NH + h) * NL + t) * DQ + e] = make_float2(ar, ai);
    }
}

// ---------------------------------------------------------------------------
// K3: EUNN recurrence, ONE element per lane (ring of 64 = the wave), one wave
// per recurrence -> 4096 waves (4/SIMD, 2x the TLP of the 2-elem scheme).
// Stage 0 partner d^1: quad_perm(1,0,3,2) DPP. Stage 1 partner d+1 (odd) /
// d-1 (even): single wave_rol:1 / wave_ror:1 DPP + cndmask by parity — the
// 64-lane wrap IS the ring wrap. Constants identical to the R2/R3-verified
// two-stage form. modrelu: exact reference form (R7 lesson — no rsqrt fold).
// ---------------------------------------------------------------------------
__device__ __forceinline__ float dpp_quad_xor1(float x) {  // lane i <- i^1
    return __int_as_float(__builtin_amdgcn_mov_dpp(__float_as_int(x), 0xB1, 0xF, 0xF, true));
}
__device__ __forceinline__ float dpp_up1(float x) {        // lane i <- (i+1)%64
    return __int_as_float(__builtin_amdgcn_mov_dpp(__float_as_int(x), 0x134, 0xF, 0xF, true));
}
__device__ __forceinline__ float dpp_dn1(float x) {        // lane i <- (i-1)%64
    return __int_as_float(__builtin_amdgcn_mov_dpp(__float_as_int(x), 0x13C, 0xF, 0xF, true));
}

__global__ __launch_bounds__(256) void rnn_kernel(
    const float* __restrict__ attn_f, const float2* __restrict__ u,
    const float* __restrict__ theta, const float* __restrict__ phi,
    const float* __restrict__ rnn_bias, float* __restrict__ rnn_out)
{
    int tid = threadIdx.x;
    int wv = tid >> 6;
    int d = tid & 63;
    int rec = blockIdx.x * 4 + wv;          // 0..4095
    int qi = rec & 255, h = (rec >> 8) & 7, b = rec >> 11;
    bool ev = (d & 1) == 0;

    const float* tb = theta + h * 64;
    const float* pb = phi + h * 64;

    // layer 0: pair j0 = d>>1, partner d^1
    int j0 = d >> 1;
    float th0 = tb[j0], ph0 = pb[j0];
    float c0 = cosf(th0), s0 = sinf(th0);
    float w0r = (ev ? -s0 : s0) * cosf(ph0);
    float w0i = -s0 * sinf(ph0);

    // layer 1: pair j1 (ev: j0-1 mod 32, odd: j0), partner ev ? d-1 : d+1
    int j1 = ev ? ((j0 + 31) & 31) : j0;
    float th1 = tb[32 + j1], ph1 = pb[32 + j1];
    float c1 = cosf(th1), s1 = sinf(th1);
    float w1r = (ev ? s1 : -s1) * cosf(ph1);
    float w1i = -s1 * sinf(ph1);

    float bias_d = rnn_bias[h * 64 + d];

    // attn rows: 4 recs x 256 steps; in-loop reads are same-address broadcasts
    __shared__ float arow[4][256];
    {
        const float4* ap = (const float4*)(attn_f + (size_t)blockIdx.x * 4 * 256);
        ((float4*)arow)[tid] = ap[tid];
    }
    __syncthreads();
    const float* arc = arow[wv];

    // u row for (b,h): lane d reads u[t][d] — 512B coalesced per wave,
    // shared by all 4 waves of the block (L1 hit after first toucher).
    const float2* up = u + (size_t)((b * NH + h) * NL) * DQ + d;

    float hr = 0.f, hi = 0.f;
    #pragma unroll 4
    for (int t = 0; t < 256; t++) {
        float2 uu = up[t * 64];
        float a_t = arc[t];

        // stage 0
        float pr = dpp_quad_xor1(hr);
        float pi = dpp_quad_xor1(hi);
        float t0r = c0 * hr + w0r * pr - w0i * pi;
        float t0i = c0 * hi + w0r * pi + w0i * pr;

        // stage 1: both rotations, select by parity
        float fur = dpp_up1(t0r), fui = dpp_up1(t0i);   // t0[d+1]
        float fdr = dpp_dn1(t0r), fdi = dpp_dn1(t0i);   // t0[d-1]
        float gr = ev ? fdr : fur;
        float gi = ev ? fdi : fui;

        float zr = c1 * t0r + w1r * gr - w1i * gi + a_t * uu.x;
        float zi = c1 * t0i + w1r * gi + w1i * gr + a_t * uu.y;

        // modrelu — exact reference form
        float mm = zr * zr + zi * zi;
        float m = __builtin_amdgcn_sqrtf(mm);
        float sc = fmaxf(m + bias_d, 0.f) * __builtin_amdgcn_rcpf(m + 1e-5f);
        hr = zr * sc;
        hi = zi * sc;
    }

    rnn_out[(size_t)(b * NL + qi) * DM + h * DQ + d] = hr;
}

// ---------------------------------------------------------------------------
// K4: output projection. 32x64 tile, K-tile 32, thread tile 2x4.
// ---------------------------------------------------------------------------
__global__ __launch_bounds__(256) void out_gemm(
    const float* __restrict__ A, const float* __restrict__ W,
    const float* __restrict__ bias, float* __restrict__ C)
{
    __shared__ float As[32][33];
    __shared__ float Bs[32][68];

    int tid = threadIdx.x;
    int tx = tid & 15, ty = tid >> 4;
    int m0 = blockIdx.y * 32, n0 = blockIdx.x * 64;

    float acc[2][4] = {};

    for (int k0 = 0; k0 < 512; k0 += 32) {
        {
            int r = tid >> 3, c4 = (tid & 7) * 4;
            const float4 av = *(const float4*)(A + (m0 + r) * 512 + k0 + c4);
            As[c4 + 0][r] = av.x; As[c4 + 1][r] = av.y;
            As[c4 + 2][r] = av.z; As[c4 + 3][r] = av.w;
        }
        {
            int r = tid >> 4, c4 = (tid & 15) * 4;
            float4 b0 = *(const float4*)(W + (k0 + r) * 512 + n0 + c4);
            float4 b1 = *(const float4*)(W + (k0 + r + 16) * 512 + n0 + c4);
            *(float4*)&Bs[r][c4] = b0;
            *(float4*)&Bs[r + 16][c4] = b1;
        }
        __syncthreads();
        #pragma unroll
        for (int kk = 0; kk < 32; kk++) {
            float a0 = As[kk][ty * 2 + 0];
            float a1 = As[kk][ty * 2 + 1];
            float4 bb = *(const float4*)&Bs[kk][tx * 4];
            acc[0][0] += a0 * bb.x; acc[0][1] += a0 * bb.y;
            acc[0][2] += a0 * bb.z; acc[0][3] += a0 * bb.w;
            acc[1][0] += a1 * bb.x; acc[1][1] += a1 * bb.y;
            acc[1][2] += a1 * bb.z; acc[1][3] += a1 * bb.w;
        }
        __syncthreads();
    }

    #pragma unroll
    for (int i = 0; i < 2; i++) {
        int m = m0 + ty * 2 + i;
        #pragma unroll
        for (int j = 0; j < 4; j++) {
            int n = n0 + tx * 4 + j;
            C[m * 512 + n] = acc[i][j] + bias[n];
        }
    }
}

// ---------------------------------------------------------------------------
extern "C" void kernel_launch(void* const* d_in, const int* in_sizes, int n_in,
                              void* d_out, int out_size, void* d_ws, size_t ws_size,
                              hipStream_t stream)
{
    const float* x_q  = (const float*)d_in[0];
    const float* x_k  = (const float*)d_in[1];
    const float* x_v  = (const float*)d_in[2];
    const float* mask = (const float*)d_in[3];
    const float* Wq   = (const float*)d_in[4];
    const float* bq   = (const float*)d_in[5];
    const float* Wk   = (const float*)d_in[6];
    const float* bk   = (const float*)d_in[7];
    const float* Wv   = (const float*)d_in[8];
    const float* bv   = (const float*)d_in[9];
    const float* Wo   = (const float*)d_in[10];
    const float* bo   = (const float*)d_in[11];
    const float* theta= (const float*)d_in[12];
    const float* phi  = (const float*)d_in[13];
    const float* Wre  = (const float*)d_in[14];
    const float* Wim  = (const float*)d_in[15];
    const float* rb   = (const float*)d_in[16];

    float* ws = (float*)d_ws;
    float*  q_ws    = ws;                       // 262144 f
    float*  kT_ws   = ws + 262144;              // 262144 f  (b,h,d,t)
    float*  v_ws    = ws + 524288;              // 262144 f
    float2* u_ws    = (float2*)(ws + 786432);   // 262144 float2
    float*  rnn_o   = ws + 1310720;             // 262144 f

    float* out_o  = (float*)d_out;              // (2,256,512)
    float* attn_o = out_o + NB * NL * DM;       // (2,8,256,256)

    qkv_gemm<<<dim3(8, 8, 3), 256, 0, stream>>>(
        x_q, x_k, x_v, Wq, Wk, Wv, bq, bk, bv, q_ws, kT_ws, v_ws);

    attn_u_kernel<<<dim3(320, NH, NB), 256, 0, stream>>>(
        q_ws, kT_ws, mask, attn_o, v_ws, Wre, Wim, u_ws);

    rnn_kernel<<<dim3(1024), 256, 0, stream>>>(
        attn_o, u_ws, theta, phi, rb, rnn_o);

    out_gemm<<<dim3(8, 16), 256, 0, stream>>>(rnn_o, Wo, bo, out_o);
}

// Round 10
// 209.993 us; speedup vs baseline: 1.0775x; 1.0318x over previous
//
#include <hip/hip_runtime.h>
#include <math.h>

#define NB 2
#define NL 256
#define DM 512
#define NH 8
#define DQ 64

// ---------------------------------------------------------------------------
// K1: QKV projection GEMM. 64x64 tile, K-tile 32, thread tile 4x4, b128 LDS
// reads. grid (8,8,3). k (z==1) written TRANSPOSED (b,h,d,t) for attn.
// ---------------------------------------------------------------------------
__global__ __launch_bounds__(256) void qkv_gemm(
    const float* __restrict__ xq, const float* __restrict__ xk,
    const float* __restrict__ xv,
    const float* __restrict__ Wq, const float* __restrict__ Wk,
    const float* __restrict__ Wv,
    const float* __restrict__ bq, const float* __restrict__ bk,
    const float* __restrict__ bv,
    float* __restrict__ q, float* __restrict__ k, float* __restrict__ v)
{
    int z = blockIdx.z;
    const float* X = (z == 0) ? xq : (z == 1) ? xk : xv;
    const float* W = (z == 0) ? Wq : (z == 1) ? Wk : Wv;
    const float* bias = (z == 0) ? bq : (z == 1) ? bk : bv;
    float* O = (z == 0) ? q : (z == 1) ? k : v;

    __shared__ float As[32][68];
    __shared__ float Bs[32][68];

    int tid = threadIdx.x;
    int tx = tid & 15, ty = tid >> 4;
    int m0 = blockIdx.y * 64, n0 = blockIdx.x * 64;

    float acc[4][4] = {};

    for (int k0 = 0; k0 < 512; k0 += 32) {
        {
            int m = tid & 63;
            int kq = tid >> 6;
            const float* src = X + (m0 + m) * 512 + k0 + kq * 4;
            float4 a0 = *(const float4*)(src);
            float4 a1 = *(const float4*)(src + 16);
            As[kq * 4 + 0][m] = a0.x; As[kq * 4 + 1][m] = a0.y;
            As[kq * 4 + 2][m] = a0.z; As[kq * 4 + 3][m] = a0.w;
            As[kq * 4 + 16][m] = a1.x; As[kq * 4 + 17][m] = a1.y;
            As[kq * 4 + 18][m] = a1.z; As[kq * 4 + 19][m] = a1.w;
        }
        {
            int r = tid >> 4, c4 = (tid & 15) * 4;
            float4 b0 = *(const float4*)(W + (k0 + r) * 512 + n0 + c4);
            float4 b1 = *(const float4*)(W + (k0 + r + 16) * 512 + n0 + c4);
            *(float4*)&Bs[r][c4] = b0;
            *(float4*)&Bs[r + 16][c4] = b1;
        }
        __syncthreads();
        #pragma unroll
        for (int kk = 0; kk < 32; kk++) {
            float4 a = *(const float4*)&As[kk][ty * 4];
            float4 bb = *(const float4*)&Bs[kk][tx * 4];
            acc[0][0] += a.x * bb.x; acc[0][1] += a.x * bb.y;
            acc[0][2] += a.x * bb.z; acc[0][3] += a.x * bb.w;
            acc[1][0] += a.y * bb.x; acc[1][1] += a.y * bb.y;
            acc[1][2] += a.y * bb.z; acc[1][3] += a.y * bb.w;
            acc[2][0] += a.z * bb.x; acc[2][1] += a.z * bb.y;
            acc[2][2] += a.z * bb.z; acc[2][3] += a.z * bb.w;
            acc[3][0] += a.w * bb.x; acc[3][1] += a.w * bb.y;
            acc[3][2] += a.w * bb.z; acc[3][3] += a.w * bb.w;
        }
        __syncthreads();
    }

    #pragma unroll
    for (int i = 0; i < 4; i++) {
        int m = m0 + ty * 4 + i;
        int b = m >> 8, l = m & 255;
        #pragma unroll
        for (int j = 0; j < 4; j++) {
            int n = n0 + tx * 4 + j;
            int h = n >> 6, d = n & 63;
            float val = acc[i][j] + bias[n];
            if (z == 1)
                O[((b * NH + h) * DQ + d) * NL + l] = val;   // kT: (b,h,d,t)
            else
                O[((b * NH + h) * NL + l) * DQ + d] = val;
        }
    }
}

// ---------------------------------------------------------------------------
// K2: fused attn softmax + u precompute. blockIdx.x<256 -> attn row, else u.
// attn reads kT coalesced.
// ---------------------------------------------------------------------------
__global__ __launch_bounds__(256) void attn_u_kernel(
    const float* __restrict__ q, const float* __restrict__ kT,
    const float* __restrict__ mask, float* __restrict__ attn_o,
    const float* __restrict__ v, const float* __restrict__ Wre,
    const float* __restrict__ Wim, float2* __restrict__ u)
{
    int h = blockIdx.y, b = blockIdx.z;
    int tid = threadIdx.x;
    __shared__ float smem[264];

    if (blockIdx.x < 256) {
        int qi = blockIdx.x;
        int wv = tid >> 6, lane = tid & 63;
        float* qrow = smem;
        float* wred = smem + 256;
        float* wsum = smem + 260;

        if (tid < 16)
            ((float4*)qrow)[tid] = ((const float4*)(q + ((b * NH + h) * NL + qi) * DQ))[tid];
        __syncthreads();

        const float* kp = kT + (size_t)((b * NH + h) * DQ) * NL + tid;
        float acc = 0.f;
        #pragma unroll
        for (int d = 0; d < 64; d++) acc += qrow[d] * kp[d * NL];
        acc *= 0.125f;

        float mv = mask[(b * NL + qi) * NL + tid];
        acc -= (mv == 1.0f) ? INFINITY : mv;

        float mx = acc;
        #pragma unroll
        for (int o = 32; o; o >>= 1) mx = fmaxf(mx, __shfl_xor(mx, o, 64));
        if (lane == 0) wred[wv] = mx;
        __syncthreads();
        mx = fmaxf(fmaxf(wred[0], wred[1]), fmaxf(wred[2], wred[3]));

        float e = __expf(acc - mx);
        float s = e;
        #pragma unroll
        for (int o = 32; o; o >>= 1) s += __shfl_xor(s, o, 64);
        if (lane == 0) wsum[wv] = s;
        __syncthreads();
        s = wsum[0] + wsum[1] + wsum[2] + wsum[3];

        attn_o[((b * NH + h) * NL + qi) * NL + tid] = e * __builtin_amdgcn_rcpf(s);
    } else {
        int xi = blockIdx.x - 256;          // 0..63
        int e = tid & 63, tq = tid >> 6;
        int t = xi * 4 + tq;
        float (*vrow)[64] = (float (*)[64])smem;

        const float* vp = v + ((b * NH + h) * NL + t) * DQ;
        vrow[tq][e] = vp[e];
        __syncthreads();

        const float* wr = Wre + h * 4096 + e;
        const float* wi = Wim + h * 4096 + e;
        float ar = 0.f, ai = 0.f;
        #pragma unroll
        for (int d = 0; d < 64; d++) {
            float vv = vrow[tq][d];
            ar += vv * wr[d * 64];
            ai += vv * wi[d * 64];
        }
        u[((b * NH + h) * NL + t) * DQ + e] = make_float2(ar, ai);
    }
}

// ---------------------------------------------------------------------------
// K3: EUNN recurrence. R6's 2-elem/lane parity-interleaved DPP scheme, plus
// TWO independent recurrence sets per wave (ILP-2 on the serial chain):
//   lane i: par = i&1 (rec within set), p = i>>1 (position 0..31);
//   wave recs = rbase + {0,1} (set0: e*) and rbase + {2,3} (set1: E*).
// All 4 recs share (b,h): coeffs, biases, and the u row are loaded ONCE.
// Cross-lane exchange = rotate-by-2 via chained DPP wave_rol/ror (pure VALU).
// modrelu: exact reference form (R7 lesson).
// ---------------------------------------------------------------------------
__device__ __forceinline__ float rot_up2(float x) {   // lane i <- lane (i+2)%64
    int v = __builtin_amdgcn_mov_dpp(__float_as_int(x), 0x134, 0xF, 0xF, true);
    v = __builtin_amdgcn_mov_dpp(v, 0x134, 0xF, 0xF, true);
    return __int_as_float(v);
}
__device__ __forceinline__ float rot_dn2(float x) {   // lane i <- lane (i-2)%64
    int v = __builtin_amdgcn_mov_dpp(__float_as_int(x), 0x13C, 0xF, 0xF, true);
    v = __builtin_amdgcn_mov_dpp(v, 0x13C, 0xF, 0xF, true);
    return __int_as_float(v);
}

__global__ __launch_bounds__(256) void rnn_kernel(
    const float* __restrict__ attn_f, const float2* __restrict__ u,
    const float* __restrict__ theta, const float* __restrict__ phi,
    const float* __restrict__ rnn_bias, float* __restrict__ rnn_out)
{
    int tid = threadIdx.x;
    int wv = tid >> 6;
    int lane = tid & 63;
    int par = lane & 1;
    int p = lane >> 1;                          // 0..31
    int rbase = blockIdx.x * 16 + wv * 4;       // block: 16 recs, same (b,h)
    int h = (rbase >> 8) & 7, b = rbase >> 11;

    const float* tb = theta + h * 64;
    const float* pb = phi + h * 64;

    // stage-0 pair j = p (verbatim R6 constants)
    float th0 = tb[p], ph0 = pb[p];
    float c0 = cosf(th0), s0 = sinf(th0);
    float cp0 = cosf(ph0), sp0 = sinf(ph0);
    float W0ar = -s0 * cp0, W0ai = -s0 * sp0;   // coeff on e1 in na
    float W0br =  s0 * cp0, W0bi = -s0 * sp0;   // coeff on e0 in nb

    // stage-1 pair j = p (output element 2p+1)
    float th1 = tb[32 + p], ph1 = pb[32 + p];
    float c1 = cosf(th1), s1 = sinf(th1);
    float W1ar = -s1 * cosf(ph1), W1ai = -s1 * sinf(ph1);   // on f1

    // stage-1 pair pm = p-1 (output element 2p)
    int pm = (p + 31) & 31;
    float th1m = tb[32 + pm], ph1m = pb[32 + pm];
    float c1m = cosf(th1m), s1m = sinf(th1m);
    float W1br = s1m * cosf(ph1m), W1bi = -s1m * sinf(ph1m); // on f2

    float bias0 = rnn_bias[h * 64 + 2 * p];
    float bias1 = rnn_bias[h * 64 + 2 * p + 1];

    // attn rows: 16 recs x 256 steps, padded stride 260 (rows land in
    // different banks; the 2-addr par0/par1 broadcast read is conflict-free)
    __shared__ float arow[16][260];
    {
        const float4* ap = (const float4*)(attn_f + (size_t)blockIdx.x * 16 * 256);
        #pragma unroll
        for (int i = 0; i < 4; i++) {
            int idx = tid + 256 * i;
            *(float4*)&arow[idx >> 6][(idx & 63) * 4] = ap[idx];
        }
    }
    __syncthreads();
    const float* a0 = arow[wv * 4 + par];        // set0 rec = rbase + par
    const float* a1 = arow[wv * 4 + 2 + par];    // set1 rec = rbase + 2 + par

    // shared u row for the whole block's (b,h); lane pair reads float4 p
    const float4* up4 = (const float4*)(u + (size_t)((b * NH + h) * NL) * DQ) + p;

    float e0r = 0.f, e0i = 0.f, e1r = 0.f, e1i = 0.f;   // set0
    float E0r = 0.f, E0i = 0.f, E1r = 0.f, E1i = 0.f;   // set1
    #pragma unroll 4
    for (int t = 0; t < 256; t++) {
        float4 uu = up4[t * 32];
        float at0 = a0[t];
        float at1 = a1[t];

        // ---- stage 0 (in-lane), both sets
        float na_r = c0 * e0r + (W0ar * e1r - W0ai * e1i);
        float na_i = c0 * e0i + (W0ar * e1i + W0ai * e1r);
        float nb_r = c0 * e1r + (W0br * e0r - W0bi * e0i);
        float nb_i = c0 * e1i + (W0br * e0i + W0bi * e0r);

        float Na_r = c0 * E0r + (W0ar * E1r - W0ai * E1i);
        float Na_i = c0 * E0i + (W0ar * E1i + W0ai * E1r);
        float Nb_r = c0 * E1r + (W0br * E0r - W0bi * E0i);
        float Nb_i = c0 * E1i + (W0br * E0i + W0bi * E0r);

        // ---- neighbor exchange via DPP, both sets
        float f1r = rot_up2(na_r), f1i = rot_up2(na_i);
        float f2r = rot_dn2(nb_r), f2i = rot_dn2(nb_i);
        float F1r = rot_up2(Na_r), F1i = rot_up2(Na_i);
        float F2r = rot_dn2(Nb_r), F2i = rot_dn2(Nb_i);

        // ---- stage 1 + input, set0
        float z1r = c1 * nb_r + (W1ar * f1r - W1ai * f1i) + at0 * uu.z;
        float z1i = c1 * nb_i + (W1ar * f1i + W1ai * f1r) + at0 * uu.w;
        float z0r = c1m * na_r + (W1br * f2r - W1bi * f2i) + at0 * uu.x;
        float z0i = c1m * na_i + (W1br * f2i + W1bi * f2r) + at0 * uu.y;
        // set1
        float Z1r = c1 * Nb_r + (W1ar * F1r - W1ai * F1i) + at1 * uu.z;
        float Z1i = c1 * Nb_i + (W1ar * F1i + W1ai * F1r) + at1 * uu.w;
        float Z0r = c1m * Na_r + (W1br * F2r - W1bi * F2i) + at1 * uu.x;
        float Z0i = c1m * Na_i + (W1br * F2i + W1bi * F2r) + at1 * uu.y;

        // ---- modrelu (exact reference form), 4 elements
        float mm0 = z0r * z0r + z0i * z0i;
        float m0 = __builtin_amdgcn_sqrtf(mm0);
        float sc0 = fmaxf(m0 + bias0, 0.f) * __builtin_amdgcn_rcpf(m0 + 1e-5f);
        e0r = z0r * sc0; e0i = z0i * sc0;

        float mm1 = z1r * z1r + z1i * z1i;
        float m1 = __builtin_amdgcn_sqrtf(mm1);
        float sc1 = fmaxf(m1 + bias1, 0.f) * __builtin_amdgcn_rcpf(m1 + 1e-5f);
        e1r = z1r * sc1; e1i = z1i * sc1;

        float MM0 = Z0r * Z0r + Z0i * Z0i;
        float M0 = __builtin_amdgcn_sqrtf(MM0);
        float SC0 = fmaxf(M0 + bias0, 0.f) * __builtin_amdgcn_rcpf(M0 + 1e-5f);
        E0r = Z0r * SC0; E0i = Z0i * SC0;

        float MM1 = Z1r * Z1r + Z1i * Z1i;
        float M1 = __builtin_amdgcn_sqrtf(MM1);
        float SC1 = fmaxf(M1 + bias1, 0.f) * __builtin_amdgcn_rcpf(M1 + 1e-5f);
        E1r = Z1r * SC1; E1i = Z1i * SC1;
    }

    // real parts -> (B, L, DM) row-major; set0 rec = rbase+par, set1 = +2
    {
        int rec0 = rbase + par;
        int rec1 = rbase + 2 + par;
        int q0 = rec0 & 255, q1 = rec1 & 255;
        *(float2*)&rnn_out[(size_t)(b * NL + q0) * DM + h * DQ + 2 * p] =
            make_float2(e0r, e1r);
        *(float2*)&rnn_out[(size_t)(b * NL + q1) * DM + h * DQ + 2 * p] =
            make_float2(E0r, E1r);
    }
}

// ---------------------------------------------------------------------------
// K4: output projection. 32x64 tile, K-tile 32, thread tile 2x4.
// ---------------------------------------------------------------------------
__global__ __launch_bounds__(256) void out_gemm(
    const float* __restrict__ A, const float* __restrict__ W,
    const float* __restrict__ bias, float* __restrict__ C)
{
    __shared__ float As[32][33];
    __shared__ float Bs[32][68];

    int tid = threadIdx.x;
    int tx = tid & 15, ty = tid >> 4;
    int m0 = blockIdx.y * 32, n0 = blockIdx.x * 64;

    float acc[2][4] = {};

    for (int k0 = 0; k0 < 512; k0 += 32) {
        {
            int r = tid >> 3, c4 = (tid & 7) * 4;
            const float4 av = *(const float4*)(A + (m0 + r) * 512 + k0 + c4);
            As[c4 + 0][r] = av.x; As[c4 + 1][r] = av.y;
            As[c4 + 2][r] = av.z; As[c4 + 3][r] = av.w;
        }
        {
            int r = tid >> 4, c4 = (tid & 15) * 4;
            float4 b0 = *(const float4*)(W + (k0 + r) * 512 + n0 + c4);
            float4 b1 = *(const float4*)(W + (k0 + r + 16) * 512 + n0 + c4);
            *(float4*)&Bs[r][c4] = b0;
            *(float4*)&Bs[r + 16][c4] = b1;
        }
        __syncthreads();
        #pragma unroll
        for (int kk = 0; kk < 32; kk++) {
            float a0 = As[kk][ty * 2 + 0];
            float a1 = As[kk][ty * 2 + 1];
            float4 bb = *(const float4*)&Bs[kk][tx * 4];
            acc[0][0] += a0 * bb.x; acc[0][1] += a0 * bb.y;
            acc[0][2] += a0 * bb.z; acc[0][3] += a0 * bb.w;
            acc[1][0] += a1 * bb.x; acc[1][1] += a1 * bb.y;
            acc[1][2] += a1 * bb.z; acc[1][3] += a1 * bb.w;
        }
        __syncthreads();
    }

    #pragma unroll
    for (int i = 0; i < 2; i++) {
        int m = m0 + ty * 2 + i;
        #pragma unroll
        for (int j = 0; j < 4; j++) {
            int n = n0 + tx * 4 + j;
            C[m * 512 + n] = acc[i][j] + bias[n];
        }
    }
}

// ---------------------------------------------------------------------------
extern "C" void kernel_launch(void* const* d_in, const int* in_sizes, int n_in,
                              void* d_out, int out_size, void* d_ws, size_t ws_size,
                              hipStream_t stream)
{
    const float* x_q  = (const float*)d_in[0];
    const float* x_k  = (const float*)d_in[1];
    const float* x_v  = (const float*)d_in[2];
    const float* mask = (const float*)d_in[3];
    const float* Wq   = (const float*)d_in[4];
    const float* bq   = (const float*)d_in[5];
    const float* Wk   = (const float*)d_in[6];
    const float* bk   = (const float*)d_in[7];
    const float* Wv   = (const float*)d_in[8];
    const float* bv   = (const float*)d_in[9];
    const float* Wo   = (const float*)d_in[10];
    const float* bo   = (const float*)d_in[11];
    const float* theta= (const float*)d_in[12];
    const float* phi  = (const float*)d_in[13];
    const float* Wre  = (const float*)d_in[14];
    const float* Wim  = (const float*)d_in[15];
    const float* rb   = (const float*)d_in[16];

    float* ws = (float*)d_ws;
    float*  q_ws    = ws;                       // 262144 f
    float*  kT_ws   = ws + 262144;              // 262144 f  (b,h,d,t)
    float*  v_ws    = ws + 524288;              // 262144 f
    float2* u_ws    = (float2*)(ws + 786432);   // 262144 float2
    float*  rnn_o   = ws + 1310720;             // 262144 f

    float* out_o  = (float*)d_out;              // (2,256,512)
    float* attn_o = out_o + NB * NL * DM;       // (2,8,256,256)

    qkv_gemm<<<dim3(8, 8, 3), 256, 0, stream>>>(
        x_q, x_k, x_v, Wq, Wk, Wv, bq, bk, bv, q_ws, kT_ws, v_ws);

    attn_u_kernel<<<dim3(320, NH, NB), 256, 0, stream>>>(
        q_ws, kT_ws, mask, attn_o, v_ws, Wre, Wim, u_ws);

    rnn_kernel<<<dim3(256), 256, 0, stream>>>(
        attn_o, u_ws, theta, phi, rb, rnn_o);

    out_gemm<<<dim3(8, 16), 256, 0, stream>>>(rnn_o, Wo, bo, out_o);
}